// Round 5
// baseline (379.125 us; speedup 1.0000x reference)
//
#include <hip/hip_runtime.h>

// MixedLayerCond round 9: cut LDS-read traffic (the measured bottleneck).
//  - r8 model closure: round = 96KB LDS reads /128B/cy *1.13 conflicts =
//    847cy ~= measured 838cy (MfmaUtil 37%). => LDS-read-BW-bound.
//  - kw-outer/kh-inner loop swap + 4-row bf register window: window slides
//    by ROW per kh step -> 2 new bf reads/step instead of 8 (2.8x cut k7).
//    wt relayout [cc][kw][kh][oc][ci] keeps the ring walk linear.
//  - afc ring-read bank fix: wave chunk swizzled to [mt][q][ln][j] in prep
//    so ds_read is byte-linear in lane (conflict-free, = DMA write pattern).
//  - xs back to 40-ushort col stride (80B: <=2-way banks; r8's 64B was 8-way).
//  - ring 2 slots (vmcnt(4)), trash slot kept for tail-exact counting.
//    LDS 30.4+32+4 = 67.3KB -> 2 blocks/CU.
//  - heavy (k>=5) quarter-cc tiles (NCC=2, 32/sample): straggler < makespan
//    at the higher per-block rate.

typedef unsigned short ushort_t;
typedef __attribute__((ext_vector_type(8))) short short8;
typedef __attribute__((ext_vector_type(4))) float f32x4;

#define CIN   256
#define COUT  256
#define HH    32
#define WW    32
#define HW    1024

// ws layout (ushort elements)
#define XT_ELEMS   16777216            // 64*8*1024*32
#define WT_OFF_0   0
#define WT_OFF_1   65536               // 8*256*1*32
#define WT_OFF_2   655360              // + 8*256*9*32
#define WT_OFF_3   2293760             // + 8*256*25*32
#define WT_ELEMS   5505024             // + 8*256*49*32
#define TILE_BYTE_OFF ((size_t)(XT_ELEMS + WT_ELEMS) * 2)
#define MAX_TILES  2048
#define WS_NEEDED  (TILE_BYTE_OFF + MAX_TILES * 2 + 64)

// LDS x tile: up to 10 rows x 38 cols x ci-stride 40 ushorts (80B)
#define XS_R_STRIDE 1520               // 38*40
#define XS_C_STRIDE 40
#define XS_ELEMS    15200              // 10*1520 (30.4 KB)
// weight ring: 4 waves x 2 slots x 2048 ushorts (4KB)
#define WR_ELEMS    16384              // 32 KB
#define TRASH_ELEMS 2048               // 4 KB shared dummy-DMA target

__device__ inline ushort_t f2bf(float f) {
    unsigned x = __builtin_bit_cast(unsigned, f);
    unsigned r = (x + 0x7FFFu + ((x >> 16) & 1u)) >> 16;
    return (ushort_t)r;
}

// ---------------- fused pre-pass: pw + px + emb-init + sched ----------------
__global__ __launch_bounds__(256) void prep_kernel(
    const float* __restrict__ x,
    const float* __restrict__ w0, const float* __restrict__ w1,
    const float* __restrict__ w2, const float* __restrict__ w3,
    const int* __restrict__ y, const int* __restrict__ arc,
    const float* __restrict__ e0, const float* __restrict__ e1,
    const float* __restrict__ e2, const float* __restrict__ e3,
    float* __restrict__ out,
    ushort_t* __restrict__ xt, ushort_t* __restrict__ wt,
    ushort_t* __restrict__ tiles, unsigned* __restrict__ cnt) {
    __shared__ float lds[2 * 32 * 49];
    const int blk = blockIdx.x;
    const int tid = threadIdx.x;

    if (blk < 4096) {                  // ---- pw: weight transform ----
        const int a   = blk >> 10;
        const int cc  = (blk >> 7) & 7;
        const int oc0 = (blk & 127) * 2;
        const int kf  = (a == 0) ? 1 : (a == 1) ? 3 : (a == 2) ? 5 : 7;
        const int kk  = kf * kf;
        const float* __restrict__ w = (a == 0) ? w0 : (a == 1) ? w1
                                    : (a == 2) ? w2 : w3;
        const size_t woff = (a == 0) ? WT_OFF_0 : (a == 1) ? WT_OFF_1
                          : (a == 2) ? WT_OFF_2 : WT_OFF_3;
        const int ckk = 32 * kk;
#pragma unroll
        for (int ocq = 0; ocq < 2; ++ocq) {
            const float* src = w + ((size_t)((oc0 + ocq) * CIN + cc * 32)) * kk;
            for (int i = tid; i < ckk; i += 256) lds[ocq * ckk + i] = src[i];
        }
        __syncthreads();
        // layout: [cc][p=kw*K+kh][wavequarter][mt][q][ln][j]
        ushort_t* dst = wt + woff;
        const int F = 2 * kk * 32;
        for (int j = tid; j < F; j += 256) {
            const int ci  = j & 31;
            const int t2  = j >> 5;
            const int khw = t2 % kk;          // source spatial = kh*kf+kw
            const int ocq = t2 / kk;
            const int kh  = khw / kf;
            const int kw  = khw % kf;
            const int p   = kw * kf + kh;     // permuted: kw-major
            const int oc  = oc0 + ocq;
            dst[(size_t)(cc * kk + p) * 8192
                + (oc >> 6) * 2048 + ((oc >> 4) & 3) * 512
                + (ci >> 3) * 128 + (oc & 15) * 8 + (ci & 7)] =
                f2bf(lds[ocq * ckk + ci * kk + khw]);
        }
    } else if (blk < 6144) {           // ---- px: x transform ----
        const int id = (blk - 4096) * 256 + tid;
        const int hw = id & 1023;
        const int cc = (id >> 10) & 7;
        const int b  = id >> 13;
        const float* src = x + ((size_t)(b * CIN + cc * 32)) * HW + hw;
        ushort_t* dst = xt + ((size_t)((b * 8 + cc) * HW + hw)) * 32;
#pragma unroll
        for (int v = 0; v < 4; ++v) {
            short8 o;
#pragma unroll
            for (int j = 0; j < 8; ++j)
                o[j] = (short)f2bf(src[(size_t)(v * 8 + j) * HW]);
            *(short8*)(dst + v * 8) = o;
        }
    } else if (blk < 10240) {          // ---- emb-init (heavy only) ----
        const int z   = blk - 6144;    // 64 samples x 64 oc-quads
        const int b   = z >> 6;
        const int a   = arc[b];
        if (a < 2) return;             // light path stores directly
        const int oc  = (z & 63) * 4 + (tid >> 6);
        const int i   = tid & 63;
        const int cls = y[b];
        const float* __restrict__ e = (a == 2) ? e2 : e3;
        const float ev = e[(size_t)cls * COUT + oc];
        float4 v = make_float4(ev, ev, ev, ev);
        float* ob = out + ((size_t)(b * COUT + oc)) * HW + i * 16;
#pragma unroll
        for (int k = 0; k < 4; ++k) *(float4*)(ob + k * 4) = v;
    } else if (tid < 64) {             // ---- sched: LPT tile list ----
        const int lane = tid;          // == sample b
        const int ab = (int)arc[lane];
        unsigned long long m[4];
#pragma unroll
        for (int v = 0; v < 4; ++v) m[v] = __ballot(ab == v);
        int gt = 0;
#pragma unroll
        for (int v = 1; v < 4; ++v) if (v > ab) gt += __popcll(m[v]);
        const unsigned long long eq = (ab == 0) ? m[0] : (ab == 1) ? m[1]
                                    : (ab == 2) ? m[2] : m[3];
        const unsigned long long lower = (lane == 0) ? 0ull
                                       : (~0ull >> (64 - lane));
        const int rank = gt + __popcll(eq & lower);
        const int nh   = __popcll(m[2]) + __popcll(m[3]);   // heavy samples
        const bool heavy = (ab >= 2);
        const int myCnt = heavy ? 32 : 8;
        const int start = heavy ? 32 * rank : 32 * nh + 8 * (rank - nh);
        for (int j = 0; j < myCnt; ++j)
            tiles[start + j] = (ushort_t)((lane << 5) | j);
        if (lane == 0) { cnt[0] = 0u; cnt[1] = (unsigned)(512 + 24 * nh); }
    }
}

// ---------------- main: MFMA conv body ----------------
// Block tile = 256oc x 4rows; wave = oc quarter (64oc), NF=8 (128 pos).
// Loop nest: cc -> s(=kw) -> kh. bf register window (4 rows x 2 halves)
// slides by row per kh step: 2 fresh ds_reads/step instead of 8.
// Weights: per-wave 2-slot LDS ring, global_load_lds 2 steps ahead,
// s_waitcnt vmcnt(4); every step issues exactly 4 loads (real or trash).
template <int K, int NCC, bool ATOMIC>
__device__ void conv_body(const ushort_t* __restrict__ xt,
                          const ushort_t* __restrict__ wtb,
                          const float* __restrict__ eb,
                          int b, int cls, int cc0, int r0,
                          float* __restrict__ out,
                          ushort_t* xs, ushort_t* wr, ushort_t* trash) {
    constexpr int KK   = K * K;
    constexpr int PAD  = K / 2;
    constexpr int R    = 4 + 2 * PAD;        // staged rows (max 10)
    constexpr int ITER = (R * 128) / 256;    // staging iters (exact)

    const int tid  = threadIdx.x;
    const int wave = tid >> 6;
    const int lane = tid & 63;
    const int ln   = lane & 15;
    const int q    = lane >> 4;

    f32x4 acc[4][8];
#pragma unroll
    for (int mt = 0; mt < 4; ++mt)
#pragma unroll
        for (int nt = 0; nt < 8; ++nt) acc[mt][nt] = (f32x4)0.0f;

    // ring: per-wave 2 slots x 2048 ushorts
    ushort_t* wrw = wr + wave * (2 * 2048);
    const ushort_t* wsrc = wtb + (size_t)wave * 2048 + (size_t)lane * 8;

    const int t0   = cc0 * KK;
    const int TEND = (cc0 + NCC) * KK;

    auto issue = [&](int idx, ushort_t* dst) {
#pragma unroll
        for (int mt = 0; mt < 4; ++mt)
            __builtin_amdgcn_global_load_lds(
                (const __attribute__((address_space(1))) void*)
                    (wsrc + (size_t)idx * 8192 + mt * 512),
                (__attribute__((address_space(3))) void*)
                    (dst + mt * 512),
                16, 0, 0);
    };

    // prologue: prime both slots (TEND-t0 >= 2 always)
    issue(t0, wrw); issue(t0 + 1, wrw + 2048);

    const ushort_t* xsrc = xt + ((size_t)b * 8) * (HW * 32);

    int rs = 0;                        // ring slot of current t
    for (int cc2 = 0; cc2 < NCC; ++cc2) {
        const int cc = cc0 + cc2;
        __syncthreads();
#pragma unroll
        for (int i = 0; i < ITER; ++i) {
            const int id = tid + i * 256;
            const int r  = id >> 7;
            const int gw = (id >> 2) & 31;
            const int g4 = id & 3;
            const int gr = r0 - PAD + r;
            short8 v = (short8)0;
            if (gr >= 0 && gr < HH)
                v = *(const short8*)&xsrc[((size_t)(cc * HW + gr * WW + gw)) * 32 + g4 * 8];
            *(short8*)&xs[r * XS_R_STRIDE + (gw + 3) * XS_C_STRIDE + g4 * 8] = v;
        }
        __syncthreads();

#pragma unroll 1
        for (int s = 0; s < K; ++s) {
            const int cbase = (ln + 3 + s - PAD) * XS_C_STRIDE + q * 8;
            // prime bf window: rows 0..3, both 16-pos halves
            short8 bw[4][2];
#pragma unroll
            for (int r = 0; r < 4; ++r)
#pragma unroll
                for (int h = 0; h < 2; ++h)
                    bw[r][h] = *(const short8*)
                        &xs[r * XS_R_STRIDE + h * (16 * XS_C_STRIDE) + cbase];
#pragma unroll
            for (int kh = 0; kh < K; ++kh) {
                const int t = cc * KK + s * K + kh;
                // exactly 4 younger loads (group t+1) outstanding post-wait
                asm volatile("s_waitcnt vmcnt(4)" ::: "memory");
                __builtin_amdgcn_sched_barrier(0);
                short8 afc[4];
#pragma unroll
                for (int mt = 0; mt < 4; ++mt)
                    afc[mt] = *(const short8*)
                        &wrw[rs * 2048 + mt * 512 + q * 128 + ln * 8];
                asm volatile("s_waitcnt lgkmcnt(0)" ::: "memory");
                __builtin_amdgcn_sched_barrier(0);
                const bool real = (t + 2 < TEND);
                issue(real ? (t + 2) : t0, real ? (wrw + rs * 2048) : trash);
                short8 nw[2];
                if (kh + 1 < K) {
#pragma unroll
                    for (int h = 0; h < 2; ++h)
                        nw[h] = *(const short8*)
                            &xs[(kh + 4) * XS_R_STRIDE + h * (16 * XS_C_STRIDE) + cbase];
                }
#pragma unroll
                for (int mt = 0; mt < 4; ++mt)
#pragma unroll
                    for (int m = 0; m < 4; ++m)
#pragma unroll
                        for (int h = 0; h < 2; ++h)
                            acc[mt][m * 2 + h] = __builtin_amdgcn_mfma_f32_16x16x32_bf16(
                                afc[mt], bw[(kh + m) & 3][h], acc[mt][m * 2 + h], 0, 0, 0);
                if (kh + 1 < K) {
                    bw[kh & 3][0] = nw[0];
                    bw[kh & 3][1] = nw[1];
                }
                rs ^= 1;
            }
        }
    }

    // epilogue: C/D layout col=lane&15 (pos), row=q*4+reg (oc)
#pragma unroll
    for (int mt = 0; mt < 4; ++mt) {
#pragma unroll
        for (int i = 0; i < 4; ++i) {
            const int oc = wave * 64 + mt * 16 + q * 4 + i;
            float* ob = out + ((size_t)(b * COUT + oc)) * HW;
            if (ATOMIC) {
#pragma unroll
                for (int nt = 0; nt < 8; ++nt) {
                    const int row = r0 + (nt >> 1);
                    const int col = (nt & 1) * 16 + ln;
                    atomicAdd(&ob[row * WW + col], acc[mt][nt][i]);
                }
            } else {
                const float ev = eb[(size_t)cls * COUT + oc];
#pragma unroll
                for (int nt = 0; nt < 8; ++nt) {
                    const int row = r0 + (nt >> 1);
                    const int col = (nt & 1) * 16 + ln;
                    ob[row * WW + col] = acc[mt][nt][i] + ev;
                }
            }
        }
    }
}

__global__ __launch_bounds__(256, 2) void conv_mfma(
    const ushort_t* __restrict__ xt, const ushort_t* __restrict__ wt,
    const int* __restrict__ y, const int* __restrict__ arc,
    const float* __restrict__ e0, const float* __restrict__ e1,
    const float* __restrict__ e2, const float* __restrict__ e3,
    float* __restrict__ out,
    const ushort_t* __restrict__ tiles, unsigned* __restrict__ cnt) {
    __shared__ ushort_t xs[XS_ELEMS];
    __shared__ ushort_t wr[WR_ELEMS];
    __shared__ ushort_t trash[TRASH_ELEMS];
    __shared__ int t_sh;
    const int tid = threadIdx.x;
    const unsigned T = cnt[1];

    // zero column halo once (cols 0-2, 35-37; staging never writes them)
    for (int i = tid; i < 240; i += 256) {
        const int g    = i & 3;
        const int cell = i >> 2;
        const int cidx = cell % 6;
        const int r    = cell / 6;
        const int col  = (cidx < 3) ? cidx : cidx + 32;
        *(short8*)&xs[r * XS_R_STRIDE + col * XS_C_STRIDE + g * 8] = (short8)0;
    }

    for (;;) {
        if (tid == 0) {
            const unsigned t = atomicAdd(cnt, 1u);
            t_sh = (t < T) ? (int)tiles[t] : -1;
        }
        __syncthreads();
        const int e = t_sh;
        __syncthreads();
        if (e < 0) break;

        const int b   = e >> 5;
        const int j   = e & 31;
        const int a   = __builtin_amdgcn_readfirstlane(arc[b]);
        const int cls = __builtin_amdgcn_readfirstlane(y[b]);
        // light: j in [0,8)  -> r0 = j*4, full depth (NCC=8)
        // heavy: j in [0,32) -> r0 = (j>>2)*4, cc0 = (j&3)*2 (NCC=2)
        switch (a) {
            case 0:  conv_body<1, 8, false>(xt, wt + WT_OFF_0, e0, b, cls,
                                            0, (j & 7) << 2, out, xs, wr, trash); break;
            case 1:  conv_body<3, 8, false>(xt, wt + WT_OFF_1, e1, b, cls,
                                            0, (j & 7) << 2, out, xs, wr, trash); break;
            case 2:  conv_body<5, 2, true>(xt, wt + WT_OFF_2, e2, b, cls,
                                           (j & 3) << 1, (j >> 2) << 2, out, xs, wr, trash); break;
            default: conv_body<7, 2, true>(xt, wt + WT_OFF_3, e3, b, cls,
                                           (j & 3) << 1, (j >> 2) << 2, out, xs, wr, trash); break;
        }
    }
}

// ---------------- fallback (round-1 direct conv) ----------------
__global__ __launch_bounds__(256) void cond_conv_direct(
    const float* __restrict__ x, const int* __restrict__ y,
    const int* __restrict__ arc,
    const float* __restrict__ w0, const float* __restrict__ e0,
    const float* __restrict__ w1, const float* __restrict__ e1,
    const float* __restrict__ w2, const float* __restrict__ e2,
    const float* __restrict__ w3, const float* __restrict__ e3,
    float* __restrict__ out) {
    const int b   = blockIdx.x >> 4;
    const int o0  = (blockIdx.x & 15) << 4;
    const int tid = threadIdx.x;
    const int col  = tid & 31;
    const int row0 = tid >> 5;
    int a   = __builtin_amdgcn_readfirstlane(arc[b]);
    int cls = __builtin_amdgcn_readfirstlane(y[b]);
    const int k   = (a == 0) ? 1 : (a == 1) ? 3 : (a == 2) ? 5 : 7;
    const int kk  = k * k;
    const int pad = k >> 1;
    const float* __restrict__ wp = (a == 0) ? w0 : (a == 1) ? w1 : (a == 2) ? w2 : w3;
    const float* __restrict__ ep = (a == 0) ? e0 : (a == 1) ? e1 : (a == 2) ? e2 : e3;
    __shared__ float xsh[8 * HW];
    float acc[16][4];
#pragma unroll
    for (int o = 0; o < 16; ++o)
#pragma unroll
        for (int p = 0; p < 4; ++p) acc[o][p] = 0.f;
    const float* xb = x + (size_t)b * CIN * HW;
    for (int c0 = 0; c0 < CIN; c0 += 8) {
        __syncthreads();
        const float4* src = (const float4*)(xb + c0 * HW);
        float4* dst = (float4*)xsh;
#pragma unroll
        for (int i = 0; i < 8; ++i) dst[tid + (i << 8)] = src[tid + (i << 8)];
        __syncthreads();
        for (int kh = 0; kh < k; ++kh) {
            const int dh = kh - pad;
            int raddr[4]; bool rok[4];
#pragma unroll
            for (int p = 0; p < 4; ++p) {
                const int rr = row0 + 8 * p + dh;
                rok[p] = (rr >= 0) && (rr < HH);
                raddr[p] = (rok[p] ? rr : 0) * WW;
            }
            for (int kw = 0; kw < k; ++kw) {
                const int cc2 = col + kw - pad;
                const bool cok = (cc2 >= 0) && (cc2 < WW);
                const int cofs = cok ? cc2 : 0;
                const int khw = kh * k + kw;
#pragma unroll
                for (int ci = 0; ci < 8; ++ci) {
                    float xv[4];
#pragma unroll
                    for (int p = 0; p < 4; ++p) {
                        const float v = xsh[ci * HW + raddr[p] + cofs];
                        xv[p] = (rok[p] && cok) ? v : 0.f;
                    }
                    const float* wb = wp + (size_t)o0 * CIN * kk + (size_t)(c0 + ci) * kk + khw;
#pragma unroll
                    for (int o = 0; o < 16; ++o) {
                        const float wsv = wb[(size_t)o * CIN * kk];
#pragma unroll
                        for (int p = 0; p < 4; ++p) acc[o][p] += wsv * xv[p];
                    }
                }
            }
        }
    }
    const float* erow = ep + (size_t)cls * COUT + o0;
    float* ob = out + (size_t)(b * COUT + o0) * HW;
#pragma unroll
    for (int o = 0; o < 16; ++o) {
        const float ev = erow[o];
#pragma unroll
        for (int p = 0; p < 4; ++p)
            ob[o * HW + (row0 + 8 * p) * WW + col] = acc[o][p] + ev;
    }
}

extern "C" void kernel_launch(void* const* d_in, const int* in_sizes, int n_in,
                              void* d_out, int out_size, void* d_ws, size_t ws_size,
                              hipStream_t stream) {
    const float* x   = (const float*)d_in[0];
    const int*   y   = (const int*)  d_in[1];
    const int*   arc = (const int*)  d_in[2];
    const float* w0  = (const float*)d_in[3];
    const float* e0  = (const float*)d_in[4];
    const float* w1  = (const float*)d_in[5];
    const float* e1  = (const float*)d_in[6];
    const float* w2  = (const float*)d_in[7];
    const float* e2  = (const float*)d_in[8];
    const float* w3  = (const float*)d_in[9];
    const float* e3  = (const float*)d_in[10];
    float* out = (float*)d_out;
    const int B = in_sizes[1];

    if (ws_size >= WS_NEEDED && B == 64) {
        ushort_t* xt    = (ushort_t*)d_ws;
        ushort_t* wt    = xt + XT_ELEMS;
        ushort_t* tiles = (ushort_t*)((char*)d_ws + TILE_BYTE_OFF);
        unsigned* cnt   = (unsigned*)((char*)d_ws + TILE_BYTE_OFF + MAX_TILES * 2);
        hipLaunchKernelGGL(prep_kernel, dim3(10241), dim3(256), 0, stream,
                           x, w0, w1, w2, w3, y, arc, e0, e1, e2, e3, out,
                           xt, wt, tiles, cnt);
        hipLaunchKernelGGL(conv_mfma, dim3(512), dim3(256), 0, stream,
                           xt, wt, y, arc, e0, e1, e2, e3, out, tiles, cnt);
    } else {
        hipLaunchKernelGGL(cond_conv_direct, dim3(B * 16), dim3(256), 0, stream,
                           x, y, arc, w0, e0, w1, e1, w2, e2, w3, e3, out);
    }
}